// Round 2
// baseline (151.317 us; speedup 1.0000x reference)
//
#include <hip/hip_runtime.h>
#include <math.h>

#define MAXN 0.996f
#define MINN 1e-15f
#define CAPQ 1536          // per-64-row-bucket capacity (mean 1024, sd ~32)

typedef __bf16   bf16x8  __attribute__((ext_vector_type(8)));
typedef _Float16 halfx8  __attribute__((ext_vector_type(8)));
typedef _Float16 half2_t __attribute__((ext_vector_type(2)));
typedef float    floatx4 __attribute__((ext_vector_type(4)));

__device__ __forceinline__ float wsum(float v){
  v += __shfl_xor(v, 32);
  v += __shfl_xor(v, 16);
  v += __shfl_xor(v, 8);
  v += __shfl_xor(v, 4);
  v += __shfl_xor(v, 2);
  v += __shfl_xor(v, 1);
  return v;
}

__device__ __forceinline__ float artanh_(float v){
  v = fminf(fmaxf(v, -1.f + 1e-7f), 1.f - 1e-7f);
  return 0.5f * (log1pf(v) - log1pf(-v));
}

// block-wide (256 thr) exclusive scan; wsums = LDS[4]; contains one __syncthreads
__device__ __forceinline__ int block_excl_scan(int v, int tid, int* wsums){
  int lane = tid & 63, wid = tid >> 6;
  int iv = v;
#pragma unroll
  for(int o = 1; o < 64; o <<= 1){
    int t = __shfl_up(iv, o);
    if(lane >= o) iv += t;
  }
  if(lane == 63) wsums[wid] = iv;
  __syncthreads();
  int wbase = 0;
  for(int k = 0; k < wid; k++) wbase += wsums[k];
  return wbase + iv - v;
}

// =================== FUSED: passA (blocks 0..nA-1) + stageA (blocks nA..) ===================
// passA now bins edges directly by 64-row bucket: bin = r >> 6 (1024 bins).
// pack: p0r = s(0:15) | (r&63)(16:21) | bin(22:31)
__global__ __launch_bounds__(256)
void fusedA_kernel(const float* __restrict__ x, const float* __restrict__ W,
                   const float* __restrict__ bias, _Float16* __restrict__ ht, int n,
                   const int* __restrict__ adj, const float* __restrict__ w,
                   float* __restrict__ adj_out, int* __restrict__ bucketSize,
                   int2* __restrict__ part, int E, int nA)
{
  __shared__ __align__(16) char smem[49408];
  const int tid = threadIdx.x;

  if(blockIdx.x < nA){
    // ---------------- passA: bucket partition (bin = r>>6) + adj->float copy ----------------
    int* hist  = (int*)smem;            // 4 KB (1024 bins, shared hist)
    int* cur   = (int*)(smem + 4096);   // 4 KB
    int* lbase = (int*)(smem + 8192);   // 4 KB
    int* gbase = (int*)(smem + 12288);  // 4 KB
    int* wsA   = (int*)(smem + 16384);  // 16 B
    int2* stag = (int2*)(smem + 16400); // 32 KB

#pragma unroll
    for(int k = 0; k < 4; k++) hist[k*256 + tid] = 0;
    __syncthreads();

    const int e0 = blockIdx.x * 4096;
    int p0r[16], p1r[16];
#pragma unroll
    for(int k = 0; k < 16; k++){
      int e = e0 + k*256 + tid;
      if(e < E){
        int s = adj[e];
        int r = adj[e + E];
        float we = w[e];
        adj_out[e]     = (float)s;
        adj_out[e + E] = (float)r;
        int bin = r >> 6;
        p0r[k] = s | ((r & 63) << 16) | (bin << 22);
        p1r[k] = __float_as_int(we);
        atomicAdd(&hist[bin], 1);
      }
    }
    __syncthreads();
    int c0 = hist[4*tid], c1 = hist[4*tid+1], c2 = hist[4*tid+2], c3 = hist[4*tid+3];
    int cb = c0 + c1 + c2 + c3;
    int lb = block_excl_scan(cb, tid, wsA);   // contains a sync
    int l0 = lb, l1 = lb + c0, l2 = l1 + c1, l3 = l2 + c2;
    lbase[4*tid] = l0; lbase[4*tid+1] = l1; lbase[4*tid+2] = l2; lbase[4*tid+3] = l3;
    cur[4*tid]   = l0; cur[4*tid+1]   = l1; cur[4*tid+2]   = l2; cur[4*tid+3]   = l3;
    gbase[4*tid]   = c0 ? atomicAdd(&bucketSize[4*tid],   c0) : 0;
    gbase[4*tid+1] = c1 ? atomicAdd(&bucketSize[4*tid+1], c1) : 0;
    gbase[4*tid+2] = c2 ? atomicAdd(&bucketSize[4*tid+2], c2) : 0;
    gbase[4*tid+3] = c3 ? atomicAdd(&bucketSize[4*tid+3], c3) : 0;
    __syncthreads();
#pragma unroll
    for(int k = 0; k < 16; k++){
      int e = e0 + k*256 + tid;
      if(e < E){
        int bin = ((unsigned)p0r[k]) >> 22;
        int pos = atomicAdd(&cur[bin], 1);
        stag[pos] = make_int2(p0r[k], p1r[k]);
      }
    }
    __syncthreads();
    int total = (e0 + 4096 <= E) ? 4096 : (E - e0);
    for(int i = tid; i < total; i += 256){
      int2 p = stag[i];
      int bin = ((unsigned)p.x) >> 22;
      int loc = gbase[bin] + (i - lbase[bin]);
      if(loc < CAPQ) part[(size_t)bin * CAPQ + loc] = p;
    }
    return;
  }

  // ---------------- stageA ----------------
  __bf16* Wh   = (__bf16*)smem;            // 32 KB
  float* hb_sh = (float*)(smem + 32768);   // 512 B
  float* y2_sh = (float*)(smem + 33280);   // 4 B

  for(int g = tid; g < 2048; g += 256){
    int nr = g >> 4, k16 = g & 15;
    const float* wp = W + nr * 128 + k16 * 8;
    float4 a = *(const float4*)wp;
    float4 b = *(const float4*)(wp + 4);
    bf16x8 h;
    h[0]=(__bf16)a.x; h[1]=(__bf16)a.y; h[2]=(__bf16)a.z; h[3]=(__bf16)a.w;
    h[4]=(__bf16)b.x; h[5]=(__bf16)b.y; h[6]=(__bf16)b.z; h[7]=(__bf16)b.w;
    *(bf16x8*)&Wh[nr * 128 + ((k16 ^ (nr & 15)) << 3)] = h;
  }
  if(tid < 64){
    int l = tid;
    float b0 = bias[l], b1 = bias[l + 64];
    float bn = fmaxf(sqrtf(wsum(b0*b0 + b1*b1)), MINN);
    float sb = tanhf(bn) / bn;
    float hb0 = sb*b0, hb1 = sb*b1;
    float hnn = fmaxf(sqrtf(wsum(hb0*hb0 + hb1*hb1)), MINN);
    if(hnn > MAXN){ float f = MAXN/hnn; hb0 *= f; hb1 *= f; }
    float y2 = wsum(hb0*hb0 + hb1*hb1);
    hb_sh[l] = hb0; hb_sh[l + 64] = hb1;
    if(l == 0) *y2_sh = y2;
  }
  __syncthreads();

  const int lane = tid & 63;
  const int wid  = tid >> 6;
  const int q    = lane >> 4;
  const int n15  = lane & 15;

  const int M0 = (blockIdx.x - nA) * 64 + wid * 16;
  if(M0 >= n) return;

  float hbv[8];
#pragma unroll
  for(int t = 0; t < 8; t++) hbv[t] = hb_sh[t*16 + n15];
  const float y2 = *y2_sh;

  floatx4 acc[8];
#pragma unroll
  for(int t = 0; t < 8; t++) acc[t] = (floatx4){0.f,0.f,0.f,0.f};

  float x2p = 0.f;
  int m = M0 + n15; if(m > n - 1) m = n - 1;
#pragma unroll
  for(int kk = 0; kk < 4; kk++){
    const float* xp = x + (size_t)m * 128 + kk * 32 + q * 8;
    float4 xa = *(const float4*)xp;
    float4 xb = *(const float4*)(xp + 4);
    x2p += xa.x*xa.x + xa.y*xa.y + xa.z*xa.z + xa.w*xa.w
         + xb.x*xb.x + xb.y*xb.y + xb.z*xb.z + xb.w*xb.w;
    bf16x8 a;
    a[0]=(__bf16)xa.x; a[1]=(__bf16)xa.y; a[2]=(__bf16)xa.z; a[3]=(__bf16)xa.w;
    a[4]=(__bf16)xb.x; a[5]=(__bf16)xb.y; a[6]=(__bf16)xb.z; a[7]=(__bf16)xb.w;
    int k16 = kk * 4 + q;
#pragma unroll
    for(int t = 0; t < 8; t++){
      bf16x8 b = *(bf16x8*)&Wh[(t*16 + n15) * 128 + ((k16 ^ n15) << 3)];
      acc[t] = __builtin_amdgcn_mfma_f32_16x16x32_bf16(a, b, acc[t], 0, 0, 0);
    }
  }
  x2p += __shfl_xor(x2p, 16);
  x2p += __shfl_xor(x2p, 32);

  float mp[4], dp[4];
#pragma unroll
  for(int i = 0; i < 4; i++){
    float mpi = 0.f, dpi = 0.f;
#pragma unroll
    for(int t = 0; t < 8; t++){ float v = acc[t][i]; mpi = fmaf(v, v, mpi); dpi = fmaf(v, hbv[t], dpi); }
    mpi += __shfl_xor(mpi, 1); mpi += __shfl_xor(mpi, 2); mpi += __shfl_xor(mpi, 4); mpi += __shfl_xor(mpi, 8);
    dpi += __shfl_xor(dpi, 1); dpi += __shfl_xor(dpi, 2); dpi += __shfl_xor(dpi, 4); dpi += __shfl_xor(dpi, 8);
    mp[i] = mpi; dp[i] = dpi;
  }

  const int li   = lane & 3;
  const int srcl = (((lane >> 2) << 4) | li) & 63;
  float selmp = li==0 ? mp[0] : li==1 ? mp[1] : li==2 ? mp[2] : mp[3];
  float seldp = li==0 ? dp[0] : li==1 ? dp[1] : li==2 ? dp[2] : dp[3];
  float tmp_mp = __shfl(selmp, srcl);
  float tmp_dp = __shfl(seldp, srcl);
  float mxn = fmaxf(sqrtf(tmp_mp), MINN);
  float xn  = fmaxf(sqrtf(x2p), MINN);
  float tt  = tanhf(mxn / xn * artanh_(xn));
  float s1  = tt / mxn;
  float rn  = fmaxf(tt, MINN);
  if(rn > MAXN) s1 *= MAXN / rn;
  float xy    = s1 * tmp_dp;
  float r2    = s1 * s1 * tmp_mp;
  float alpha = 1.f + 2.f*xy + y2;
  float beta  = 1.f - r2;
  float inv   = 1.f / fmaxf(1.f + 2.f*xy + r2*y2, MINN);
  float as1   = alpha * s1;

  float as1b[4], betab[4], invb[4];
#pragma unroll
  for(int i = 0; i < 4; i++){
    int sl = ((lane >> 4) << 2) | i;
    as1b[i]  = __shfl(as1, sl);
    betab[i] = __shfl(beta, sl);
    invb[i]  = __shfl(inv, sl);
  }

  float uv[4][8];
  float u2[4];
#pragma unroll
  for(int i = 0; i < 4; i++){
    float u2i = 0.f;
#pragma unroll
    for(int t = 0; t < 8; t++){
      float u = (as1b[i] * acc[t][i] + betab[i] * hbv[t]) * invb[i];
      uv[i][t] = u;
      u2i = fmaf(u, u, u2i);
    }
    u2i += __shfl_xor(u2i, 1); u2i += __shfl_xor(u2i, 2); u2i += __shfl_xor(u2i, 4); u2i += __shfl_xor(u2i, 8);
    u2[i] = u2i;
  }

  float selu = li==0 ? u2[0] : li==1 ? u2[1] : li==2 ? u2[2] : u2[3];
  float tu   = __shfl(selu, srcl);
  float un = fmaxf(sqrtf(tu), MINN);
  float sc = 1.f, hn = un;
  if(un > MAXN){ sc = MAXN/un; hn = MAXN; }
  float lt = artanh_(hn) / hn * sc;

#pragma unroll
  for(int i = 0; i < 4; i++){
    int grow = M0 + q * 4 + i;
    float lti = __shfl(lt, ((lane >> 4) << 2) | i);
    if(grow < n){
      halfx8 f;
#pragma unroll
      for(int t = 0; t < 8; t++) f[t] = (_Float16)(lti * uv[i][t]);
      *(halfx8*)(ht + (size_t)grow * 128 + n15 * 8) = f;
    }
  }
}

// ======= FUSED aggregate + HypAct: one 64-row bucket per block, 512 thr / 8 waves =======
// Phase 1: read own segment of part (<=3 edges/thread in regs), build 64-row CSR in LDS.
// Phase 2: 32 groups of 16 lanes, 2 rows/group -> gather ht + weighted sum + HypAct.
__global__ __launch_bounds__(512)
void aggB_kernel(const int* __restrict__ bucketSize, const int2* __restrict__ part,
                 const _Float16* __restrict__ ht, float* __restrict__ out, int n)
{
  __shared__ unsigned epk_l[CAPQ];    // 6 KB
  __shared__ int hist[64];
  __shared__ int rowoff[65];
  __shared__ int cursor[64];
  __shared__ float tr[8][4][132];     // 16.9 KB

  const int tid = threadIdx.x;
  const int b   = blockIdx.x;

  if(tid < 64) hist[tid] = 0;
  __syncthreads();

  int size = bucketSize[b]; if(size > CAPQ) size = CAPQ;
  const int2* src = part + (size_t)b * CAPQ;
  int2 e0v, e1v, e2v;
  const bool v0 = tid < size;
  const bool v1 = tid + 512 < size;
  const bool v2 = tid + 1024 < size;
  if(v0) e0v = src[tid];
  if(v1) e1v = src[tid + 512];
  if(v2) e2v = src[tid + 1024];
  if(v0) atomicAdd(&hist[(((unsigned)e0v.x) >> 16) & 63], 1);
  if(v1) atomicAdd(&hist[(((unsigned)e1v.x) >> 16) & 63], 1);
  if(v2) atomicAdd(&hist[(((unsigned)e2v.x) >> 16) & 63], 1);
  __syncthreads();
  if(tid < 64){
    int v = hist[tid];
    int iv = v;
#pragma unroll
    for(int o = 1; o < 64; o <<= 1){ int t = __shfl_up(iv, o); if(tid >= o) iv += t; }
    rowoff[tid + 1] = iv;
    cursor[tid]     = iv - v;
    if(tid == 0) rowoff[0] = 0;
  }
  __syncthreads();
#define PUTE(ev) { \
    int rl = (((unsigned)ev.x) >> 16) & 63; \
    int p = atomicAdd(&cursor[rl], 1); \
    unsigned wh = (unsigned)__builtin_bit_cast(unsigned short, \
                    (_Float16)__builtin_bit_cast(float, ev.y)); \
    epk_l[p] = (unsigned)(ev.x & 0xFFFF) | (wh << 16); }
  if(v0) PUTE(e0v);
  if(v1) PUTE(e1v);
  if(v2) PUTE(e2v);
#undef PUTE
  __syncthreads();

  // ---------------- phase 2: aggregation + HypAct (2 rows per 16-lane group) ----------------
  const int gi   = tid >> 4;         // 0..31
  const int i    = tid & 15;
  const int wid  = tid >> 6;         // 0..7
  const int g    = (tid >> 4) & 3;
  const char* htb = (const char*)ht;
  const int ioff = i << 4;

#define EDGE(pk) { \
    int s_ = (int)((pk) & 0xFFFFu); \
    half2_t w2_ = __builtin_bit_cast(half2_t, __builtin_amdgcn_perm(pk, pk, 0x03020302u)); \
    int4 q_ = *(const int4*)(htb + ((s_ << 8) | ioff)); \
    acc2[0] = __builtin_bit_cast(half2_t, q_.x) * w2_ + acc2[0]; \
    acc2[1] = __builtin_bit_cast(half2_t, q_.y) * w2_ + acc2[1]; \
    acc2[2] = __builtin_bit_cast(half2_t, q_.z) * w2_ + acc2[2]; \
    acc2[3] = __builtin_bit_cast(half2_t, q_.w) * w2_ + acc2[3]; \
  }

  for(int rp = 0; rp < 2; rp++){
    const int lr  = gi + rp * 32;    // local row 0..63
    const int row = b * 64 + lr;

    half2_t acc2[4];
#pragma unroll
    for(int k = 0; k < 4; k++) acc2[k] = (half2_t){(_Float16)0.f, (_Float16)0.f};

    if(row < n){
      int beg = rowoff[lr];
      int m   = rowoff[lr + 1] - beg;
      int t = 0;
      for(; t + 1 < m; t += 2){
        unsigned pk0 = epk_l[beg + t];
        unsigned pk1 = epk_l[beg + t + 1];
        EDGE(pk0);
        EDGE(pk1);
      }
      if(t < m){ unsigned pk0 = epk_l[beg + t]; EDGE(pk0); }
    }

    // epilogue: per-group (16-lane)
    float acc[8];
#pragma unroll
    for(int k = 0; k < 4; k++){
      acc[2*k]   = (float)acc2[k][0];
      acc[2*k+1] = (float)acc2[k][1];
    }
    float u2p = 0.f;
#pragma unroll
    for(int k = 0; k < 8; k++) u2p = fmaf(acc[k], acc[k], u2p);
    u2p += __shfl_xor(u2p, 1); u2p += __shfl_xor(u2p, 2);
    u2p += __shfl_xor(u2p, 4); u2p += __shfl_xor(u2p, 8);
    float un = fmaxf(sqrtf(u2p), MINN);
    float te = tanhf(un);
    float se = te / un;
    float gn = fmaxf(te, MINN);
    float hn = gn;
    if(gn > MAXN){ se *= MAXN/gn; hn = MAXN; }
    float la = artanh_(hn) / hn * se;
    float l[8];
    float r2p = 0.f;
#pragma unroll
    for(int k = 0; k < 8; k++){ l[k] = fmaxf(la*acc[k], 0.f); r2p = fmaf(l[k], l[k], r2p); }
    r2p += __shfl_xor(r2p, 1); r2p += __shfl_xor(r2p, 2);
    r2p += __shfl_xor(r2p, 4); r2p += __shfl_xor(r2p, 8);
    float rn = fmaxf(sqrtf(r2p), MINN);
    float t2 = tanhf(rn);
    float s2 = t2 / rn;
    float on = fmaxf(t2, MINN);
    if(on > MAXN) s2 *= MAXN/on;

    // un-permute via per-group LDS transpose: true dim of acc[k] is k*16+i
    // (same 16 lanes write then read their own tr slot -> wave-coherent, no barrier)
    if(row < n){
#pragma unroll
      for(int k = 0; k < 8; k++) tr[wid][g][k*16 + i] = s2 * l[k];
      float4 o0 = *(float4*)&tr[wid][g][i*8];
      float4 o1 = *(float4*)&tr[wid][g][i*8 + 4];
      float* orow = out + (size_t)row * 128 + i*8;
      *(float4*)orow       = o0;
      *(float4*)(orow + 4) = o1;
    }
  }
#undef EDGE
}

extern "C" void kernel_launch(void* const* d_in, const int* in_sizes, int n_in,
                              void* d_out, int out_size, void* d_ws, size_t ws_size,
                              hipStream_t stream)
{
  const float* x    = (const float*)d_in[0];
  const int*   adj  = (const int*)  d_in[1];
  const float* w    = (const float*)d_in[2];
  const float* W    = (const float*)d_in[3];
  const float* bias = (const float*)d_in[4];
  const int n = in_sizes[0] / 128;   // 50000
  const int E = in_sizes[2];         // 800000

  float* out     = (float*)d_out;
  float* adj_out = out + (size_t)n * 128;

  char* ws = (char*)d_ws;
  _Float16* ht   = (_Float16*)ws;  ws += (size_t)n * 128 * sizeof(_Float16);    // 12.8 MB
  int2*  part    = (int2*)ws;      ws += (size_t)1024 * CAPQ * sizeof(int2);    // 12.6 MB
  int*   bucketSize = (int*)ws;                                                 // 4 KB

  const int nA = (E + 4095) / 4096;   // 196 passA blocks
  const int nS = (n + 63) / 64;       // 782 stageA blocks
  const int nB = (n + 63) / 64;       // 782 aggregation buckets (64 rows each)

  hipMemsetAsync(bucketSize, 0, 1024 * sizeof(int), stream);
  fusedA_kernel<<<nA + nS, 256, 0, stream>>>(x, W, bias, ht, n,
                                             adj, w, adj_out, bucketSize, part, E, nA);
  aggB_kernel<<<nB, 512, 0, stream>>>(bucketSize, part, ht, out, n);
}

// Round 3
// 148.182 us; speedup vs baseline: 1.0212x; 1.0212x over previous
//
#include <hip/hip_runtime.h>
#include <math.h>

#define MAXN 0.996f
#define MINN 1e-15f
#define CAPQ 1536          // per-64-row-bucket capacity (mean 1024, sd ~32)

typedef __bf16   bf16x8  __attribute__((ext_vector_type(8)));
typedef _Float16 halfx8  __attribute__((ext_vector_type(8)));
typedef _Float16 half2_t __attribute__((ext_vector_type(2)));
typedef float    floatx4 __attribute__((ext_vector_type(4)));

__device__ __forceinline__ float wsum(float v){
  v += __shfl_xor(v, 32);
  v += __shfl_xor(v, 16);
  v += __shfl_xor(v, 8);
  v += __shfl_xor(v, 4);
  v += __shfl_xor(v, 2);
  v += __shfl_xor(v, 1);
  return v;
}

__device__ __forceinline__ float artanh_(float v){
  v = fminf(fmaxf(v, -1.f + 1e-7f), 1.f - 1e-7f);
  return 0.5f * (log1pf(v) - log1pf(-v));
}

// block-wide (256 thr) exclusive scan; wsums = LDS[4]; contains one __syncthreads
__device__ __forceinline__ int block_excl_scan(int v, int tid, int* wsums){
  int lane = tid & 63, wid = tid >> 6;
  int iv = v;
#pragma unroll
  for(int o = 1; o < 64; o <<= 1){
    int t = __shfl_up(iv, o);
    if(lane >= o) iv += t;
  }
  if(lane == 63) wsums[wid] = iv;
  __syncthreads();
  int wbase = 0;
  for(int k = 0; k < wid; k++) wbase += wsums[k];
  return wbase + iv - v;
}

// =================== FUSED: passA (blocks 0..nA-1) + stageA (blocks nA..) ===================
// passA bins edges directly by 64-row bucket: bin = r >> 6 (1024 bins).
// pack: p0r = s(0:15) | (r&63)(16:21) | bin(22:31)
__global__ __launch_bounds__(256)
void fusedA_kernel(const float* __restrict__ x, const float* __restrict__ W,
                   const float* __restrict__ bias, _Float16* __restrict__ ht, int n,
                   const int* __restrict__ adj, const float* __restrict__ w,
                   float* __restrict__ adj_out, int* __restrict__ bucketSize,
                   int2* __restrict__ part, int E, int nA)
{
  __shared__ __align__(16) char smem[49408];
  const int tid = threadIdx.x;

  if(blockIdx.x < nA){
    // ---------------- passA: bucket partition (bin = r>>6) + adj->float copy ----------------
    int* hist  = (int*)smem;            // 4 KB (1024 bins, shared hist)
    int* cur   = (int*)(smem + 4096);   // 4 KB
    int* lbase = (int*)(smem + 8192);   // 4 KB
    int* gbase = (int*)(smem + 12288);  // 4 KB
    int* wsA   = (int*)(smem + 16384);  // 16 B
    int2* stag = (int2*)(smem + 16400); // 32 KB

#pragma unroll
    for(int k = 0; k < 4; k++) hist[k*256 + tid] = 0;
    __syncthreads();

    const int e0 = blockIdx.x * 4096;
    int p0r[16], p1r[16];
#pragma unroll
    for(int k = 0; k < 16; k++){
      int e = e0 + k*256 + tid;
      if(e < E){
        int s = adj[e];
        int r = adj[e + E];
        float we = w[e];
        adj_out[e]     = (float)s;
        adj_out[e + E] = (float)r;
        int bin = r >> 6;
        p0r[k] = s | ((r & 63) << 16) | (bin << 22);
        p1r[k] = __float_as_int(we);
        atomicAdd(&hist[bin], 1);
      }
    }
    __syncthreads();
    int c0 = hist[4*tid], c1 = hist[4*tid+1], c2 = hist[4*tid+2], c3 = hist[4*tid+3];
    int cb = c0 + c1 + c2 + c3;
    int lb = block_excl_scan(cb, tid, wsA);   // contains a sync
    int l0 = lb, l1 = lb + c0, l2 = l1 + c1, l3 = l2 + c2;
    lbase[4*tid] = l0; lbase[4*tid+1] = l1; lbase[4*tid+2] = l2; lbase[4*tid+3] = l3;
    cur[4*tid]   = l0; cur[4*tid+1]   = l1; cur[4*tid+2]   = l2; cur[4*tid+3]   = l3;
    gbase[4*tid]   = c0 ? atomicAdd(&bucketSize[4*tid],   c0) : 0;
    gbase[4*tid+1] = c1 ? atomicAdd(&bucketSize[4*tid+1], c1) : 0;
    gbase[4*tid+2] = c2 ? atomicAdd(&bucketSize[4*tid+2], c2) : 0;
    gbase[4*tid+3] = c3 ? atomicAdd(&bucketSize[4*tid+3], c3) : 0;
    __syncthreads();
#pragma unroll
    for(int k = 0; k < 16; k++){
      int e = e0 + k*256 + tid;
      if(e < E){
        int bin = ((unsigned)p0r[k]) >> 22;
        int pos = atomicAdd(&cur[bin], 1);
        stag[pos] = make_int2(p0r[k], p1r[k]);
      }
    }
    __syncthreads();
    int total = (e0 + 4096 <= E) ? 4096 : (E - e0);
    for(int i = tid; i < total; i += 256){
      int2 p = stag[i];
      int bin = ((unsigned)p.x) >> 22;
      int loc = gbase[bin] + (i - lbase[bin]);
      if(loc < CAPQ) part[(size_t)bin * CAPQ + loc] = p;
    }
    return;
  }

  // ---------------- stageA ----------------
  __bf16* Wh   = (__bf16*)smem;            // 32 KB
  float* hb_sh = (float*)(smem + 32768);   // 512 B
  float* y2_sh = (float*)(smem + 33280);   // 4 B

  for(int g = tid; g < 2048; g += 256){
    int nr = g >> 4, k16 = g & 15;
    const float* wp = W + nr * 128 + k16 * 8;
    float4 a = *(const float4*)wp;
    float4 b = *(const float4*)(wp + 4);
    bf16x8 h;
    h[0]=(__bf16)a.x; h[1]=(__bf16)a.y; h[2]=(__bf16)a.z; h[3]=(__bf16)a.w;
    h[4]=(__bf16)b.x; h[5]=(__bf16)b.y; h[6]=(__bf16)b.z; h[7]=(__bf16)b.w;
    *(bf16x8*)&Wh[nr * 128 + ((k16 ^ (nr & 15)) << 3)] = h;
  }
  if(tid < 64){
    int l = tid;
    float b0 = bias[l], b1 = bias[l + 64];
    float bn = fmaxf(sqrtf(wsum(b0*b0 + b1*b1)), MINN);
    float sb = tanhf(bn) / bn;
    float hb0 = sb*b0, hb1 = sb*b1;
    float hnn = fmaxf(sqrtf(wsum(hb0*hb0 + hb1*hb1)), MINN);
    if(hnn > MAXN){ float f = MAXN/hnn; hb0 *= f; hb1 *= f; }
    float y2 = wsum(hb0*hb0 + hb1*hb1);
    hb_sh[l] = hb0; hb_sh[l + 64] = hb1;
    if(l == 0) *y2_sh = y2;
  }
  __syncthreads();

  const int lane = tid & 63;
  const int wid  = tid >> 6;
  const int q    = lane >> 4;
  const int n15  = lane & 15;

  const int M0 = (blockIdx.x - nA) * 64 + wid * 16;
  if(M0 >= n) return;

  float hbv[8];
#pragma unroll
  for(int t = 0; t < 8; t++) hbv[t] = hb_sh[t*16 + n15];
  const float y2 = *y2_sh;

  floatx4 acc[8];
#pragma unroll
  for(int t = 0; t < 8; t++) acc[t] = (floatx4){0.f,0.f,0.f,0.f};

  float x2p = 0.f;
  int m = M0 + n15; if(m > n - 1) m = n - 1;
#pragma unroll
  for(int kk = 0; kk < 4; kk++){
    const float* xp = x + (size_t)m * 128 + kk * 32 + q * 8;
    float4 xa = *(const float4*)xp;
    float4 xb = *(const float4*)(xp + 4);
    x2p += xa.x*xa.x + xa.y*xa.y + xa.z*xa.z + xa.w*xa.w
         + xb.x*xb.x + xb.y*xb.y + xb.z*xb.z + xb.w*xb.w;
    bf16x8 a;
    a[0]=(__bf16)xa.x; a[1]=(__bf16)xa.y; a[2]=(__bf16)xa.z; a[3]=(__bf16)xa.w;
    a[4]=(__bf16)xb.x; a[5]=(__bf16)xb.y; a[6]=(__bf16)xb.z; a[7]=(__bf16)xb.w;
    int k16 = kk * 4 + q;
#pragma unroll
    for(int t = 0; t < 8; t++){
      bf16x8 b = *(bf16x8*)&Wh[(t*16 + n15) * 128 + ((k16 ^ n15) << 3)];
      acc[t] = __builtin_amdgcn_mfma_f32_16x16x32_bf16(a, b, acc[t], 0, 0, 0);
    }
  }
  x2p += __shfl_xor(x2p, 16);
  x2p += __shfl_xor(x2p, 32);

  float mp[4], dp[4];
#pragma unroll
  for(int i = 0; i < 4; i++){
    float mpi = 0.f, dpi = 0.f;
#pragma unroll
    for(int t = 0; t < 8; t++){ float v = acc[t][i]; mpi = fmaf(v, v, mpi); dpi = fmaf(v, hbv[t], dpi); }
    mpi += __shfl_xor(mpi, 1); mpi += __shfl_xor(mpi, 2); mpi += __shfl_xor(mpi, 4); mpi += __shfl_xor(mpi, 8);
    dpi += __shfl_xor(dpi, 1); dpi += __shfl_xor(dpi, 2); dpi += __shfl_xor(dpi, 4); dpi += __shfl_xor(dpi, 8);
    mp[i] = mpi; dp[i] = dpi;
  }

  const int li   = lane & 3;
  const int srcl = (((lane >> 2) << 4) | li) & 63;
  float selmp = li==0 ? mp[0] : li==1 ? mp[1] : li==2 ? mp[2] : mp[3];
  float seldp = li==0 ? dp[0] : li==1 ? dp[1] : li==2 ? dp[2] : dp[3];
  float tmp_mp = __shfl(selmp, srcl);
  float tmp_dp = __shfl(seldp, srcl);
  float mxn = fmaxf(sqrtf(tmp_mp), MINN);
  float xn  = fmaxf(sqrtf(x2p), MINN);
  float tt  = tanhf(mxn / xn * artanh_(xn));
  float s1  = tt / mxn;
  float rn  = fmaxf(tt, MINN);
  if(rn > MAXN) s1 *= MAXN / rn;
  float xy    = s1 * tmp_dp;
  float r2    = s1 * s1 * tmp_mp;
  float alpha = 1.f + 2.f*xy + y2;
  float beta  = 1.f - r2;
  float inv   = 1.f / fmaxf(1.f + 2.f*xy + r2*y2, MINN);
  float as1   = alpha * s1;

  float as1b[4], betab[4], invb[4];
#pragma unroll
  for(int i = 0; i < 4; i++){
    int sl = ((lane >> 4) << 2) | i;
    as1b[i]  = __shfl(as1, sl);
    betab[i] = __shfl(beta, sl);
    invb[i]  = __shfl(inv, sl);
  }

  float uv[4][8];
  float u2[4];
#pragma unroll
  for(int i = 0; i < 4; i++){
    float u2i = 0.f;
#pragma unroll
    for(int t = 0; t < 8; t++){
      float u = (as1b[i] * acc[t][i] + betab[i] * hbv[t]) * invb[i];
      uv[i][t] = u;
      u2i = fmaf(u, u, u2i);
    }
    u2i += __shfl_xor(u2i, 1); u2i += __shfl_xor(u2i, 2); u2i += __shfl_xor(u2i, 4); u2i += __shfl_xor(u2i, 8);
    u2[i] = u2i;
  }

  float selu = li==0 ? u2[0] : li==1 ? u2[1] : li==2 ? u2[2] : u2[3];
  float tu   = __shfl(selu, srcl);
  float un = fmaxf(sqrtf(tu), MINN);
  float sc = 1.f, hn = un;
  if(un > MAXN){ sc = MAXN/un; hn = MAXN; }
  float lt = artanh_(hn) / hn * sc;

#pragma unroll
  for(int i = 0; i < 4; i++){
    int grow = M0 + q * 4 + i;
    float lti = __shfl(lt, ((lane >> 4) << 2) | i);
    if(grow < n){
      halfx8 f;
#pragma unroll
      for(int t = 0; t < 8; t++) f[t] = (_Float16)(lti * uv[i][t]);
      *(halfx8*)(ht + (size_t)grow * 128 + n15 * 8) = f;
    }
  }
}

// ======= FUSED aggregate + HypAct: one 64-row bucket per block, 1024 thr / 16 waves =======
// Phase 1: read own part segment (<=2 edges/thread in regs), build 64-row CSR in LDS.
// Phase 2: 64 groups of 16 lanes, 1 row/group -> max gather-stream count; 4-deep unroll.
__global__ __launch_bounds__(1024)
void aggB_kernel(const int* __restrict__ bucketSize, const int2* __restrict__ part,
                 const _Float16* __restrict__ ht, float* __restrict__ out, int n)
{
  __shared__ unsigned epk_l[CAPQ];    // 6 KB
  __shared__ int hist[64];
  __shared__ int rowoff[65];
  __shared__ int cursor[64];
  __shared__ float tr[16][4][132];    // 33.8 KB

  const int tid = threadIdx.x;
  const int b   = blockIdx.x;

  if(tid < 64) hist[tid] = 0;
  __syncthreads();

  int size = bucketSize[b]; if(size > CAPQ) size = CAPQ;
  const int2* src = part + (size_t)b * CAPQ;
  int2 e0v, e1v;
  const bool v0 = tid < size;
  const bool v1 = tid + 1024 < size;
  if(v0) e0v = src[tid];
  if(v1) e1v = src[tid + 1024];
  if(v0) atomicAdd(&hist[(((unsigned)e0v.x) >> 16) & 63], 1);
  if(v1) atomicAdd(&hist[(((unsigned)e1v.x) >> 16) & 63], 1);
  __syncthreads();
  if(tid < 64){
    int v = hist[tid];
    int iv = v;
#pragma unroll
    for(int o = 1; o < 64; o <<= 1){ int t = __shfl_up(iv, o); if(tid >= o) iv += t; }
    rowoff[tid + 1] = iv;
    cursor[tid]     = iv - v;
    if(tid == 0) rowoff[0] = 0;
  }
  __syncthreads();
#define PUTE(ev) { \
    int rl = (((unsigned)ev.x) >> 16) & 63; \
    int p = atomicAdd(&cursor[rl], 1); \
    unsigned wh = (unsigned)__builtin_bit_cast(unsigned short, \
                    (_Float16)__builtin_bit_cast(float, ev.y)); \
    epk_l[p] = (unsigned)(ev.x & 0xFFFF) | (wh << 16); }
  if(v0) PUTE(e0v);
  if(v1) PUTE(e1v);
#undef PUTE
  __syncthreads();

  // ---------------- phase 2: aggregation + HypAct (1 row per 16-lane group) ----------------
  const int gi   = tid >> 4;         // 0..63: local row
  const int i    = tid & 15;
  const int wid  = tid >> 6;         // 0..15
  const int g    = (tid >> 4) & 3;
  const int row  = b * 64 + gi;
  const char* htb = (const char*)ht;
  const int ioff = i << 4;

  half2_t acc2[4];
#pragma unroll
  for(int k = 0; k < 4; k++) acc2[k] = (half2_t){(_Float16)0.f, (_Float16)0.f};

#define EDGE(pk) { \
    int s_ = (int)((pk) & 0xFFFFu); \
    half2_t w2_ = __builtin_bit_cast(half2_t, __builtin_amdgcn_perm(pk, pk, 0x03020302u)); \
    int4 q_ = *(const int4*)(htb + ((s_ << 8) | ioff)); \
    acc2[0] = __builtin_bit_cast(half2_t, q_.x) * w2_ + acc2[0]; \
    acc2[1] = __builtin_bit_cast(half2_t, q_.y) * w2_ + acc2[1]; \
    acc2[2] = __builtin_bit_cast(half2_t, q_.z) * w2_ + acc2[2]; \
    acc2[3] = __builtin_bit_cast(half2_t, q_.w) * w2_ + acc2[3]; \
  }

  if(row < n){
    int beg = rowoff[gi];
    int m   = rowoff[gi + 1] - beg;
    const unsigned* ep = epk_l + beg;
    int t = 0;
    for(; t + 3 < m; t += 4){
      unsigned pk0 = ep[t], pk1 = ep[t+1], pk2 = ep[t+2], pk3 = ep[t+3];
      EDGE(pk0); EDGE(pk1); EDGE(pk2); EDGE(pk3);
    }
    for(; t + 1 < m; t += 2){
      unsigned pk0 = ep[t], pk1 = ep[t+1];
      EDGE(pk0); EDGE(pk1);
    }
    if(t < m){ unsigned pk0 = ep[t]; EDGE(pk0); }
  }
#undef EDGE

  // epilogue: per-group (16-lane) — one chain serves 4 rows per wave
  float acc[8];
#pragma unroll
  for(int k = 0; k < 4; k++){
    acc[2*k]   = (float)acc2[k][0];
    acc[2*k+1] = (float)acc2[k][1];
  }
  float u2p = 0.f;
#pragma unroll
  for(int k = 0; k < 8; k++) u2p = fmaf(acc[k], acc[k], u2p);
  u2p += __shfl_xor(u2p, 1); u2p += __shfl_xor(u2p, 2);
  u2p += __shfl_xor(u2p, 4); u2p += __shfl_xor(u2p, 8);
  float un = fmaxf(sqrtf(u2p), MINN);
  float te = tanhf(un);
  float se = te / un;
  float gn = fmaxf(te, MINN);
  float hn = gn;
  if(gn > MAXN){ se *= MAXN/gn; hn = MAXN; }
  float la = artanh_(hn) / hn * se;
  float l[8];
  float r2p = 0.f;
#pragma unroll
  for(int k = 0; k < 8; k++){ l[k] = fmaxf(la*acc[k], 0.f); r2p = fmaf(l[k], l[k], r2p); }
  r2p += __shfl_xor(r2p, 1); r2p += __shfl_xor(r2p, 2);
  r2p += __shfl_xor(r2p, 4); r2p += __shfl_xor(r2p, 8);
  float rn = fmaxf(sqrtf(r2p), MINN);
  float t2 = tanhf(rn);
  float s2 = t2 / rn;
  float on = fmaxf(t2, MINN);
  if(on > MAXN) s2 *= MAXN/on;

  // un-permute via per-group LDS transpose: true dim of acc[k] is k*16+i
  // (same 16 lanes write then read their own tr slot -> wave-coherent, no barrier)
  if(row < n){
#pragma unroll
    for(int k = 0; k < 8; k++) tr[wid][g][k*16 + i] = s2 * l[k];
    float4 o0 = *(float4*)&tr[wid][g][i*8];
    float4 o1 = *(float4*)&tr[wid][g][i*8 + 4];
    float* orow = out + (size_t)row * 128 + i*8;
    *(float4*)orow       = o0;
    *(float4*)(orow + 4) = o1;
  }
}

extern "C" void kernel_launch(void* const* d_in, const int* in_sizes, int n_in,
                              void* d_out, int out_size, void* d_ws, size_t ws_size,
                              hipStream_t stream)
{
  const float* x    = (const float*)d_in[0];
  const int*   adj  = (const int*)  d_in[1];
  const float* w    = (const float*)d_in[2];
  const float* W    = (const float*)d_in[3];
  const float* bias = (const float*)d_in[4];
  const int n = in_sizes[0] / 128;   // 50000
  const int E = in_sizes[2];         // 800000

  float* out     = (float*)d_out;
  float* adj_out = out + (size_t)n * 128;

  char* ws = (char*)d_ws;
  _Float16* ht   = (_Float16*)ws;  ws += (size_t)n * 128 * sizeof(_Float16);    // 12.8 MB
  int2*  part    = (int2*)ws;      ws += (size_t)1024 * CAPQ * sizeof(int2);    // 12.6 MB
  int*   bucketSize = (int*)ws;                                                 // 4 KB

  const int nA = (E + 4095) / 4096;   // 196 passA blocks
  const int nS = (n + 63) / 64;       // 782 stageA blocks
  const int nB = (n + 63) / 64;       // 782 aggregation buckets (64 rows each)

  hipMemsetAsync(bucketSize, 0, 1024 * sizeof(int), stream);
  fusedA_kernel<<<nA + nS, 256, 0, stream>>>(x, W, bias, ht, n,
                                             adj, w, adj_out, bucketSize, part, E, nA);
  aggB_kernel<<<nB, 1024, 0, stream>>>(bucketSize, part, ht, out, n);
}

// Round 4
// 134.323 us; speedup vs baseline: 1.1265x; 1.1032x over previous
//
#include <hip/hip_runtime.h>
#include <math.h>

#define MAXN 0.996f
#define MINN 1e-15f
#define CAPQ 1536          // per-64-row-bucket capacity (mean 1024, sd ~32)

typedef __bf16   bf16x8  __attribute__((ext_vector_type(8)));
typedef _Float16 halfx8  __attribute__((ext_vector_type(8)));
typedef _Float16 half2_t __attribute__((ext_vector_type(2)));
typedef float    floatx4 __attribute__((ext_vector_type(4)));

__device__ __forceinline__ float wsum(float v){
  v += __shfl_xor(v, 32);
  v += __shfl_xor(v, 16);
  v += __shfl_xor(v, 8);
  v += __shfl_xor(v, 4);
  v += __shfl_xor(v, 2);
  v += __shfl_xor(v, 1);
  return v;
}

__device__ __forceinline__ float artanh_(float v){
  v = fminf(fmaxf(v, -1.f + 1e-7f), 1.f - 1e-7f);
  return 0.5f * (log1pf(v) - log1pf(-v));
}

// =================== FUSED: passA (blocks 0..nA-1) + stageA (blocks nA..) ===================
// passA bins edges by 64-row bucket (bin = r>>6, 1024 bins) with DIRECT global scatter:
// no LDS staging sort, no block scan -> passA LDS = 8 KB; kernel LDS = 32 KB (Wh) -> 5 blk/CU.
// pack: p0r = s(0:15) | (r&63)(16:21) | bin(22:31)
__global__ __launch_bounds__(256)
void fusedA_kernel(const float* __restrict__ x, const float* __restrict__ W,
                   const float* __restrict__ bias, _Float16* __restrict__ ht, int n,
                   const int* __restrict__ adj, const float* __restrict__ w,
                   float* __restrict__ adj_out, int* __restrict__ bucketSize,
                   int2* __restrict__ part, int E, int nA)
{
  __shared__ __align__(16) char smem[32768];
  const int tid = threadIdx.x;

  if(blockIdx.x < nA){
    // ---------------- passA: hist -> global-base -> direct scatter ----------------
    int* hist = (int*)smem;            // 4 KB (1024 bins)
    int* cur  = (int*)(smem + 4096);   // 4 KB

#pragma unroll
    for(int k = 0; k < 4; k++) hist[k*256 + tid] = 0;
    __syncthreads();

    const int e0 = blockIdx.x * 4096;
    int p0r[16], p1r[16];
#pragma unroll
    for(int k = 0; k < 16; k++){
      int e = e0 + k*256 + tid;
      if(e < E){
        int s = adj[e];
        int r = adj[e + E];
        float we = w[e];
        adj_out[e]     = (float)s;
        adj_out[e + E] = (float)r;
        int bin = r >> 6;
        p0r[k] = s | ((r & 63) << 16) | (bin << 22);
        p1r[k] = __float_as_int(we);
        atomicAdd(&hist[bin], 1);
      }
    }
    __syncthreads();
#pragma unroll
    for(int k = 0; k < 4; k++){
      int bin = k*256 + tid;
      int c = hist[bin];
      cur[bin] = c ? atomicAdd(&bucketSize[bin], c) : 0;
    }
    __syncthreads();
#pragma unroll
    for(int k = 0; k < 16; k++){
      int e = e0 + k*256 + tid;
      if(e < E){
        int bin = ((unsigned)p0r[k]) >> 22;
        int pos = atomicAdd(&cur[bin], 1);
        if(pos < CAPQ) part[(size_t)bin * CAPQ + pos] = make_int2(p0r[k], p1r[k]);
      }
    }
    return;
  }

  // ---------------- stageA ----------------
  __bf16* Wh = (__bf16*)smem;            // exactly 32 KB

  for(int g = tid; g < 2048; g += 256){
    int nr = g >> 4, k16 = g & 15;
    const float* wp = W + nr * 128 + k16 * 8;
    float4 a = *(const float4*)wp;
    float4 b = *(const float4*)(wp + 4);
    bf16x8 h;
    h[0]=(__bf16)a.x; h[1]=(__bf16)a.y; h[2]=(__bf16)a.z; h[3]=(__bf16)a.w;
    h[4]=(__bf16)b.x; h[5]=(__bf16)b.y; h[6]=(__bf16)b.z; h[7]=(__bf16)b.w;
    *(bf16x8*)&Wh[nr * 128 + ((k16 ^ (nr & 15)) << 3)] = h;
  }

  const int lane = tid & 63;
  const int wid  = tid >> 6;
  const int q    = lane >> 4;
  const int n15  = lane & 15;

  // per-wave hyperbolic bias (redundant per wave; replaces LDS hb_sh/y2_sh)
  float b0 = bias[lane], b1 = bias[lane + 64];
  float bn = fmaxf(sqrtf(wsum(b0*b0 + b1*b1)), MINN);
  float sb = tanhf(bn) / bn;
  float hb0 = sb*b0, hb1 = sb*b1;
  float hnn = fmaxf(sqrtf(wsum(hb0*hb0 + hb1*hb1)), MINN);
  if(hnn > MAXN){ float f = MAXN/hnn; hb0 *= f; hb1 *= f; }
  const float y2 = wsum(hb0*hb0 + hb1*hb1);
  float hbv[8];
#pragma unroll
  for(int t = 0; t < 4; t++) hbv[t]     = __shfl(hb0, t*16 + n15);
#pragma unroll
  for(int t = 0; t < 4; t++) hbv[t + 4] = __shfl(hb1, t*16 + n15);

  __syncthreads();

  const int M0 = (blockIdx.x - nA) * 64 + wid * 16;
  if(M0 >= n) return;

  floatx4 acc[8];
#pragma unroll
  for(int t = 0; t < 8; t++) acc[t] = (floatx4){0.f,0.f,0.f,0.f};

  float x2p = 0.f;
  int m = M0 + n15; if(m > n - 1) m = n - 1;
#pragma unroll
  for(int kk = 0; kk < 4; kk++){
    const float* xp = x + (size_t)m * 128 + kk * 32 + q * 8;
    float4 xa = *(const float4*)xp;
    float4 xb = *(const float4*)(xp + 4);
    x2p += xa.x*xa.x + xa.y*xa.y + xa.z*xa.z + xa.w*xa.w
         + xb.x*xb.x + xb.y*xb.y + xb.z*xb.z + xb.w*xb.w;
    bf16x8 a;
    a[0]=(__bf16)xa.x; a[1]=(__bf16)xa.y; a[2]=(__bf16)xa.z; a[3]=(__bf16)xa.w;
    a[4]=(__bf16)xb.x; a[5]=(__bf16)xb.y; a[6]=(__bf16)xb.z; a[7]=(__bf16)xb.w;
    int k16 = kk * 4 + q;
#pragma unroll
    for(int t = 0; t < 8; t++){
      bf16x8 b = *(bf16x8*)&Wh[(t*16 + n15) * 128 + ((k16 ^ n15) << 3)];
      acc[t] = __builtin_amdgcn_mfma_f32_16x16x32_bf16(a, b, acc[t], 0, 0, 0);
    }
  }
  x2p += __shfl_xor(x2p, 16);
  x2p += __shfl_xor(x2p, 32);

  float mp[4], dp[4];
#pragma unroll
  for(int i = 0; i < 4; i++){
    float mpi = 0.f, dpi = 0.f;
#pragma unroll
    for(int t = 0; t < 8; t++){ float v = acc[t][i]; mpi = fmaf(v, v, mpi); dpi = fmaf(v, hbv[t], dpi); }
    mpi += __shfl_xor(mpi, 1); mpi += __shfl_xor(mpi, 2); mpi += __shfl_xor(mpi, 4); mpi += __shfl_xor(mpi, 8);
    dpi += __shfl_xor(dpi, 1); dpi += __shfl_xor(dpi, 2); dpi += __shfl_xor(dpi, 4); dpi += __shfl_xor(dpi, 8);
    mp[i] = mpi; dp[i] = dpi;
  }

  const int li   = lane & 3;
  const int srcl = (((lane >> 2) << 4) | li) & 63;
  float selmp = li==0 ? mp[0] : li==1 ? mp[1] : li==2 ? mp[2] : mp[3];
  float seldp = li==0 ? dp[0] : li==1 ? dp[1] : li==2 ? dp[2] : dp[3];
  float tmp_mp = __shfl(selmp, srcl);
  float tmp_dp = __shfl(seldp, srcl);
  float mxn = fmaxf(sqrtf(tmp_mp), MINN);
  float xn  = fmaxf(sqrtf(x2p), MINN);
  float tt  = tanhf(mxn / xn * artanh_(xn));
  float s1  = tt / mxn;
  float rn  = fmaxf(tt, MINN);
  if(rn > MAXN) s1 *= MAXN / rn;
  float xy    = s1 * tmp_dp;
  float r2    = s1 * s1 * tmp_mp;
  float alpha = 1.f + 2.f*xy + y2;
  float beta  = 1.f - r2;
  float inv   = 1.f / fmaxf(1.f + 2.f*xy + r2*y2, MINN);
  float as1   = alpha * s1;

  float as1b[4], betab[4], invb[4];
#pragma unroll
  for(int i = 0; i < 4; i++){
    int sl = ((lane >> 4) << 2) | i;
    as1b[i]  = __shfl(as1, sl);
    betab[i] = __shfl(beta, sl);
    invb[i]  = __shfl(inv, sl);
  }

  float uv[4][8];
  float u2[4];
#pragma unroll
  for(int i = 0; i < 4; i++){
    float u2i = 0.f;
#pragma unroll
    for(int t = 0; t < 8; t++){
      float u = (as1b[i] * acc[t][i] + betab[i] * hbv[t]) * invb[i];
      uv[i][t] = u;
      u2i = fmaf(u, u, u2i);
    }
    u2i += __shfl_xor(u2i, 1); u2i += __shfl_xor(u2i, 2); u2i += __shfl_xor(u2i, 4); u2i += __shfl_xor(u2i, 8);
    u2[i] = u2i;
  }

  float selu = li==0 ? u2[0] : li==1 ? u2[1] : li==2 ? u2[2] : u2[3];
  float tu   = __shfl(selu, srcl);
  float un = fmaxf(sqrtf(tu), MINN);
  float sc = 1.f, hn = un;
  if(un > MAXN){ sc = MAXN/un; hn = MAXN; }
  float lt = artanh_(hn) / hn * sc;

#pragma unroll
  for(int i = 0; i < 4; i++){
    int grow = M0 + q * 4 + i;
    float lti = __shfl(lt, ((lane >> 4) << 2) | i);
    if(grow < n){
      halfx8 f;
#pragma unroll
      for(int t = 0; t < 8; t++) f[t] = (_Float16)(lti * uv[i][t]);
      *(halfx8*)(ht + (size_t)grow * 128 + n15 * 8) = f;
    }
  }
}

// ======= FUSED aggregate + HypAct: one 64-row bucket per block, 1024 thr / 16 waves =======
// Phase 1: read own part segment (<=2 edges/thread in regs), build 64-row CSR in LDS.
// Phase 2: 64 groups of 16 lanes, 1 row/group -> max gather-stream count; 4-deep unroll.
__global__ __launch_bounds__(1024)
void aggB_kernel(const int* __restrict__ bucketSize, const int2* __restrict__ part,
                 const _Float16* __restrict__ ht, float* __restrict__ out, int n)
{
  __shared__ unsigned epk_l[CAPQ];    // 6 KB
  __shared__ int hist[64];
  __shared__ int rowoff[65];
  __shared__ int cursor[64];
  __shared__ float tr[16][4][132];    // 33.8 KB

  const int tid = threadIdx.x;
  const int b   = blockIdx.x;

  if(tid < 64) hist[tid] = 0;
  __syncthreads();

  int size = bucketSize[b]; if(size > CAPQ) size = CAPQ;
  const int2* src = part + (size_t)b * CAPQ;
  int2 e0v, e1v;
  const bool v0 = tid < size;
  const bool v1 = tid + 1024 < size;
  if(v0) e0v = src[tid];
  if(v1) e1v = src[tid + 1024];
  if(v0) atomicAdd(&hist[(((unsigned)e0v.x) >> 16) & 63], 1);
  if(v1) atomicAdd(&hist[(((unsigned)e1v.x) >> 16) & 63], 1);
  __syncthreads();
  if(tid < 64){
    int v = hist[tid];
    int iv = v;
#pragma unroll
    for(int o = 1; o < 64; o <<= 1){ int t = __shfl_up(iv, o); if(tid >= o) iv += t; }
    rowoff[tid + 1] = iv;
    cursor[tid]     = iv - v;
    if(tid == 0) rowoff[0] = 0;
  }
  __syncthreads();
#define PUTE(ev) { \
    int rl = (((unsigned)ev.x) >> 16) & 63; \
    int p = atomicAdd(&cursor[rl], 1); \
    unsigned wh = (unsigned)__builtin_bit_cast(unsigned short, \
                    (_Float16)__builtin_bit_cast(float, ev.y)); \
    epk_l[p] = (unsigned)(ev.x & 0xFFFF) | (wh << 16); }
  if(v0) PUTE(e0v);
  if(v1) PUTE(e1v);
#undef PUTE
  __syncthreads();

  // ---------------- phase 2: aggregation + HypAct (1 row per 16-lane group) ----------------
  const int gi   = tid >> 4;         // 0..63: local row
  const int i    = tid & 15;
  const int wid  = tid >> 6;         // 0..15
  const int g    = (tid >> 4) & 3;
  const int row  = b * 64 + gi;
  const char* htb = (const char*)ht;
  const int ioff = i << 4;

  half2_t acc2[4];
#pragma unroll
  for(int k = 0; k < 4; k++) acc2[k] = (half2_t){(_Float16)0.f, (_Float16)0.f};

#define EDGE(pk) { \
    int s_ = (int)((pk) & 0xFFFFu); \
    half2_t w2_ = __builtin_bit_cast(half2_t, __builtin_amdgcn_perm(pk, pk, 0x03020302u)); \
    int4 q_ = *(const int4*)(htb + ((s_ << 8) | ioff)); \
    acc2[0] = __builtin_bit_cast(half2_t, q_.x) * w2_ + acc2[0]; \
    acc2[1] = __builtin_bit_cast(half2_t, q_.y) * w2_ + acc2[1]; \
    acc2[2] = __builtin_bit_cast(half2_t, q_.z) * w2_ + acc2[2]; \
    acc2[3] = __builtin_bit_cast(half2_t, q_.w) * w2_ + acc2[3]; \
  }

  if(row < n){
    int beg = rowoff[gi];
    int m   = rowoff[gi + 1] - beg;
    const unsigned* ep = epk_l + beg;
    int t = 0;
    for(; t + 3 < m; t += 4){
      unsigned pk0 = ep[t], pk1 = ep[t+1], pk2 = ep[t+2], pk3 = ep[t+3];
      EDGE(pk0); EDGE(pk1); EDGE(pk2); EDGE(pk3);
    }
    for(; t + 1 < m; t += 2){
      unsigned pk0 = ep[t], pk1 = ep[t+1];
      EDGE(pk0); EDGE(pk1);
    }
    if(t < m){ unsigned pk0 = ep[t]; EDGE(pk0); }
  }
#undef EDGE

  // epilogue: per-group (16-lane) — one chain serves 4 rows per wave
  float acc[8];
#pragma unroll
  for(int k = 0; k < 4; k++){
    acc[2*k]   = (float)acc2[k][0];
    acc[2*k+1] = (float)acc2[k][1];
  }
  float u2p = 0.f;
#pragma unroll
  for(int k = 0; k < 8; k++) u2p = fmaf(acc[k], acc[k], u2p);
  u2p += __shfl_xor(u2p, 1); u2p += __shfl_xor(u2p, 2);
  u2p += __shfl_xor(u2p, 4); u2p += __shfl_xor(u2p, 8);
  float un = fmaxf(sqrtf(u2p), MINN);
  float te = tanhf(un);
  float se = te / un;
  float gn = fmaxf(te, MINN);
  float hn = gn;
  if(gn > MAXN){ se *= MAXN/gn; hn = MAXN; }
  float la = artanh_(hn) / hn * se;
  float l[8];
  float r2p = 0.f;
#pragma unroll
  for(int k = 0; k < 8; k++){ l[k] = fmaxf(la*acc[k], 0.f); r2p = fmaf(l[k], l[k], r2p); }
  r2p += __shfl_xor(r2p, 1); r2p += __shfl_xor(r2p, 2);
  r2p += __shfl_xor(r2p, 4); r2p += __shfl_xor(r2p, 8);
  float rn = fmaxf(sqrtf(r2p), MINN);
  float t2 = tanhf(rn);
  float s2 = t2 / rn;
  float on = fmaxf(t2, MINN);
  if(on > MAXN) s2 *= MAXN/on;

  // un-permute via per-group LDS transpose: true dim of acc[k] is k*16+i
  // (same 16 lanes write then read their own tr slot -> wave-coherent, no barrier)
  if(row < n){
#pragma unroll
    for(int k = 0; k < 8; k++) tr[wid][g][k*16 + i] = s2 * l[k];
    float4 o0 = *(float4*)&tr[wid][g][i*8];
    float4 o1 = *(float4*)&tr[wid][g][i*8 + 4];
    float* orow = out + (size_t)row * 128 + i*8;
    *(float4*)orow       = o0;
    *(float4*)(orow + 4) = o1;
  }
}

extern "C" void kernel_launch(void* const* d_in, const int* in_sizes, int n_in,
                              void* d_out, int out_size, void* d_ws, size_t ws_size,
                              hipStream_t stream)
{
  const float* x    = (const float*)d_in[0];
  const int*   adj  = (const int*)  d_in[1];
  const float* w    = (const float*)d_in[2];
  const float* W    = (const float*)d_in[3];
  const float* bias = (const float*)d_in[4];
  const int n = in_sizes[0] / 128;   // 50000
  const int E = in_sizes[2];         // 800000

  float* out     = (float*)d_out;
  float* adj_out = out + (size_t)n * 128;

  char* ws = (char*)d_ws;
  _Float16* ht   = (_Float16*)ws;  ws += (size_t)n * 128 * sizeof(_Float16);    // 12.8 MB
  int2*  part    = (int2*)ws;      ws += (size_t)1024 * CAPQ * sizeof(int2);    // 12.6 MB
  int*   bucketSize = (int*)ws;                                                 // 4 KB

  const int nA = (E + 4095) / 4096;   // 196 passA blocks
  const int nS = (n + 63) / 64;       // 782 stageA blocks
  const int nB = (n + 63) / 64;       // 782 aggregation buckets (64 rows each)

  hipMemsetAsync(bucketSize, 0, 1024 * sizeof(int), stream);
  fusedA_kernel<<<nA + nS, 256, 0, stream>>>(x, W, bias, ht, n,
                                             adj, w, adj_out, bucketSize, part, E, nA);
  aggB_kernel<<<nB, 1024, 0, stream>>>(bucketSize, part, ht, out, n);
}

// Round 5
// 134.232 us; speedup vs baseline: 1.1273x; 1.0007x over previous
//
#include <hip/hip_runtime.h>
#include <math.h>

#define MAXN 0.996f
#define MINN 1e-15f
#define CAPQ 1536          // per-64-row-bucket capacity (mean 1024, sd ~32)

typedef __bf16   bf16x8  __attribute__((ext_vector_type(8)));
typedef _Float16 halfx8  __attribute__((ext_vector_type(8)));
typedef _Float16 half2_t __attribute__((ext_vector_type(2)));
typedef float    floatx4 __attribute__((ext_vector_type(4)));

__device__ __forceinline__ float wsum(float v){
  v += __shfl_xor(v, 32);
  v += __shfl_xor(v, 16);
  v += __shfl_xor(v, 8);
  v += __shfl_xor(v, 4);
  v += __shfl_xor(v, 2);
  v += __shfl_xor(v, 1);
  return v;
}

__device__ __forceinline__ float artanh_(float v){
  v = fminf(fmaxf(v, -1.f + 1e-7f), 1.f - 1e-7f);
  return 0.5f * (log1pf(v) - log1pf(-v));
}

// =================== FUSED: passA (blocks 0..nA-1) + stageA (blocks nA..) ===================
// passA bins edges by 64-row bucket (bin = r>>6, 1024 bins) with DIRECT global scatter.
// stageA writes ht in NATURAL dim order (transpose via per-wave reuse of Wh LDS after barrier)
// so aggB needs no un-permute. Kernel LDS = 32 KB -> 5 blk/CU.
// pack: p0r = s(0:15) | (r&63)(16:21) | bin(22:31)
__global__ __launch_bounds__(256)
void fusedA_kernel(const float* __restrict__ x, const float* __restrict__ W,
                   const float* __restrict__ bias, _Float16* __restrict__ ht, int n,
                   const int* __restrict__ adj, const float* __restrict__ w,
                   float* __restrict__ adj_out, int* __restrict__ bucketSize,
                   int2* __restrict__ part, int E, int nA)
{
  __shared__ __align__(16) char smem[32768];
  const int tid = threadIdx.x;

  if(blockIdx.x < nA){
    // ---------------- passA: hist -> global-base -> direct scatter ----------------
    int* hist = (int*)smem;            // 4 KB (1024 bins)
    int* cur  = (int*)(smem + 4096);   // 4 KB

#pragma unroll
    for(int k = 0; k < 4; k++) hist[k*256 + tid] = 0;
    __syncthreads();

    const int e0 = blockIdx.x * 4096;
    int p0r[16], p1r[16];
#pragma unroll
    for(int k = 0; k < 16; k++){
      int e = e0 + k*256 + tid;
      if(e < E){
        int s = adj[e];
        int r = adj[e + E];
        float we = w[e];
        adj_out[e]     = (float)s;
        adj_out[e + E] = (float)r;
        int bin = r >> 6;
        p0r[k] = s | ((r & 63) << 16) | (bin << 22);
        p1r[k] = __float_as_int(we);
        atomicAdd(&hist[bin], 1);
      }
    }
    __syncthreads();
#pragma unroll
    for(int k = 0; k < 4; k++){
      int bin = k*256 + tid;
      int c = hist[bin];
      cur[bin] = c ? atomicAdd(&bucketSize[bin], c) : 0;
    }
    __syncthreads();
#pragma unroll
    for(int k = 0; k < 16; k++){
      int e = e0 + k*256 + tid;
      if(e < E){
        int bin = ((unsigned)p0r[k]) >> 22;
        int pos = atomicAdd(&cur[bin], 1);
        if(pos < CAPQ) part[(size_t)bin * CAPQ + pos] = make_int2(p0r[k], p1r[k]);
      }
    }
    return;
  }

  // ---------------- stageA ----------------
  __bf16* Wh = (__bf16*)smem;            // exactly 32 KB (reused as transpose scratch later)

  for(int g = tid; g < 2048; g += 256){
    int nr = g >> 4, k16 = g & 15;
    const float* wp = W + nr * 128 + k16 * 8;
    float4 a = *(const float4*)wp;
    float4 b = *(const float4*)(wp + 4);
    bf16x8 h;
    h[0]=(__bf16)a.x; h[1]=(__bf16)a.y; h[2]=(__bf16)a.z; h[3]=(__bf16)a.w;
    h[4]=(__bf16)b.x; h[5]=(__bf16)b.y; h[6]=(__bf16)b.z; h[7]=(__bf16)b.w;
    *(bf16x8*)&Wh[nr * 128 + ((k16 ^ (nr & 15)) << 3)] = h;
  }

  const int lane = tid & 63;
  const int wid  = tid >> 6;
  const int q    = lane >> 4;
  const int n15  = lane & 15;

  // per-wave hyperbolic bias (redundant per wave)
  float b0 = bias[lane], b1 = bias[lane + 64];
  float bn = fmaxf(sqrtf(wsum(b0*b0 + b1*b1)), MINN);
  float sb = tanhf(bn) / bn;
  float hb0 = sb*b0, hb1 = sb*b1;
  float hnn = fmaxf(sqrtf(wsum(hb0*hb0 + hb1*hb1)), MINN);
  if(hnn > MAXN){ float f = MAXN/hnn; hb0 *= f; hb1 *= f; }
  const float y2 = wsum(hb0*hb0 + hb1*hb1);
  float hbv[8];
#pragma unroll
  for(int t = 0; t < 4; t++) hbv[t]     = __shfl(hb0, t*16 + n15);
#pragma unroll
  for(int t = 0; t < 4; t++) hbv[t + 4] = __shfl(hb1, t*16 + n15);

  __syncthreads();   // Wh ready

  const int M0 = (blockIdx.x - nA) * 64 + wid * 16;
  // NOTE: no early return — all waves must reach the scratch-reuse barrier below.

  floatx4 acc[8];
#pragma unroll
  for(int t = 0; t < 8; t++) acc[t] = (floatx4){0.f,0.f,0.f,0.f};

  float x2p = 0.f;
  int m = M0 + n15; if(m > n - 1) m = n - 1; if(m < 0) m = 0;
#pragma unroll
  for(int kk = 0; kk < 4; kk++){
    const float* xp = x + (size_t)m * 128 + kk * 32 + q * 8;
    float4 xa = *(const float4*)xp;
    float4 xb = *(const float4*)(xp + 4);
    x2p += xa.x*xa.x + xa.y*xa.y + xa.z*xa.z + xa.w*xa.w
         + xb.x*xb.x + xb.y*xb.y + xb.z*xb.z + xb.w*xb.w;
    bf16x8 a;
    a[0]=(__bf16)xa.x; a[1]=(__bf16)xa.y; a[2]=(__bf16)xa.z; a[3]=(__bf16)xa.w;
    a[4]=(__bf16)xb.x; a[5]=(__bf16)xb.y; a[6]=(__bf16)xb.z; a[7]=(__bf16)xb.w;
    int k16 = kk * 4 + q;
#pragma unroll
    for(int t = 0; t < 8; t++){
      bf16x8 b = *(bf16x8*)&Wh[(t*16 + n15) * 128 + ((k16 ^ n15) << 3)];
      acc[t] = __builtin_amdgcn_mfma_f32_16x16x32_bf16(a, b, acc[t], 0, 0, 0);
    }
  }
  x2p += __shfl_xor(x2p, 16);
  x2p += __shfl_xor(x2p, 32);

  float mp[4], dp[4];
#pragma unroll
  for(int i = 0; i < 4; i++){
    float mpi = 0.f, dpi = 0.f;
#pragma unroll
    for(int t = 0; t < 8; t++){ float v = acc[t][i]; mpi = fmaf(v, v, mpi); dpi = fmaf(v, hbv[t], dpi); }
    mpi += __shfl_xor(mpi, 1); mpi += __shfl_xor(mpi, 2); mpi += __shfl_xor(mpi, 4); mpi += __shfl_xor(mpi, 8);
    dpi += __shfl_xor(dpi, 1); dpi += __shfl_xor(dpi, 2); dpi += __shfl_xor(dpi, 4); dpi += __shfl_xor(dpi, 8);
    mp[i] = mpi; dp[i] = dpi;
  }

  const int li   = lane & 3;
  const int srcl = (((lane >> 2) << 4) | li) & 63;
  float selmp = li==0 ? mp[0] : li==1 ? mp[1] : li==2 ? mp[2] : mp[3];
  float seldp = li==0 ? dp[0] : li==1 ? dp[1] : li==2 ? dp[2] : dp[3];
  float tmp_mp = __shfl(selmp, srcl);
  float tmp_dp = __shfl(seldp, srcl);
  float mxn = fmaxf(sqrtf(tmp_mp), MINN);
  float xn  = fmaxf(sqrtf(x2p), MINN);
  float tt  = tanhf(mxn / xn * artanh_(xn));
  float s1  = tt / mxn;
  float rn  = fmaxf(tt, MINN);
  if(rn > MAXN) s1 *= MAXN / rn;
  float xy    = s1 * tmp_dp;
  float r2    = s1 * s1 * tmp_mp;
  float alpha = 1.f + 2.f*xy + y2;
  float beta  = 1.f - r2;
  float inv   = 1.f / fmaxf(1.f + 2.f*xy + r2*y2, MINN);
  float as1   = alpha * s1;

  float as1b[4], betab[4], invb[4];
#pragma unroll
  for(int i = 0; i < 4; i++){
    int sl = ((lane >> 4) << 2) | i;
    as1b[i]  = __shfl(as1, sl);
    betab[i] = __shfl(beta, sl);
    invb[i]  = __shfl(inv, sl);
  }

  float uv[4][8];
  float u2[4];
#pragma unroll
  for(int i = 0; i < 4; i++){
    float u2i = 0.f;
#pragma unroll
    for(int t = 0; t < 8; t++){
      float u = (as1b[i] * acc[t][i] + betab[i] * hbv[t]) * invb[i];
      uv[i][t] = u;
      u2i = fmaf(u, u, u2i);
    }
    u2i += __shfl_xor(u2i, 1); u2i += __shfl_xor(u2i, 2); u2i += __shfl_xor(u2i, 4); u2i += __shfl_xor(u2i, 8);
    u2[i] = u2i;
  }

  float selu = li==0 ? u2[0] : li==1 ? u2[1] : li==2 ? u2[2] : u2[3];
  float tu   = __shfl(selu, srcl);
  float un = fmaxf(sqrtf(tu), MINN);
  float sc = 1.f, hn = un;
  if(un > MAXN){ sc = MAXN/un; hn = MAXN; }
  float lt = artanh_(hn) / hn * sc;

  // ---- natural-order ht write: scatter fp16 into per-wave LDS scratch (reused Wh), ----
  // ---- then linear readback + coalesced global store. Swizzle ^((row&7)<<4) bytes.  ----
  __syncthreads();   // ALL waves done reading Wh -> safe to reuse as scratch
  _Float16* scr = (_Float16*)(smem + (wid << 12));   // 4 KB per wave (16 rows x 256 B)

#pragma unroll
  for(int i = 0; i < 4; i++){
    int rl = q * 4 + i;                       // local row 0..15
    float lti = __shfl(lt, ((lane >> 4) << 2) | i);
    int swz = (rl & 7) << 3;                  // in halves (== <<4 bytes)
#pragma unroll
    for(int t = 0; t < 8; t++){
      scr[rl * 128 + ((t*16 + n15) ^ swz)] = (_Float16)(lti * uv[i][t]);
    }
  }
  // intra-wave LDS dependency only; compiler inserts lgkmcnt wait before the reads below
#pragma unroll
  for(int rep = 0; rep < 4; rep++){
    int fb    = rep * 1024 + lane * 16;       // byte within this wave's 4 KB tile
    int row   = fb >> 8;                      // 0..15
    int inner = fb & 255;
    int grow2 = M0 + row;
    halfx8 v = *(halfx8*)((char*)scr + row * 256 + (inner ^ ((row & 7) << 4)));
    if(grow2 < n) *(halfx8*)((char*)ht + (size_t)grow2 * 256 + inner) = v;
  }
}

// ======= FUSED aggregate + HypAct: 64-row bucket per block, 512 thr / 8 waves =======
// Natural-order ht: lane i of an 8-lane group owns dims 16i..16i+15 (contiguous).
// No transpose buffer; LDS ~7 KB -> 4 blocks/CU (wave-capped), 782 blocks all resident.
__global__ __launch_bounds__(512)
void aggB_kernel(const int* __restrict__ bucketSize, const int2* __restrict__ part,
                 const _Float16* __restrict__ ht, float* __restrict__ out, int n)
{
  __shared__ unsigned epk_l[CAPQ];    // 6 KB
  __shared__ int hist[64];
  __shared__ int rowoff[65];
  __shared__ int cursor[64];

  const int tid = threadIdx.x;
  const int b   = blockIdx.x;

  if(tid < 64) hist[tid] = 0;
  __syncthreads();

  int size = bucketSize[b]; if(size > CAPQ) size = CAPQ;
  const int2* src = part + (size_t)b * CAPQ;
  int2 e0v, e1v, e2v;
  const bool v0 = tid < size;
  const bool v1 = tid + 512 < size;
  const bool v2 = tid + 1024 < size;
  if(v0) e0v = src[tid];
  if(v1) e1v = src[tid + 512];
  if(v2) e2v = src[tid + 1024];
  if(v0) atomicAdd(&hist[(((unsigned)e0v.x) >> 16) & 63], 1);
  if(v1) atomicAdd(&hist[(((unsigned)e1v.x) >> 16) & 63], 1);
  if(v2) atomicAdd(&hist[(((unsigned)e2v.x) >> 16) & 63], 1);
  __syncthreads();
  if(tid < 64){
    int v = hist[tid];
    int iv = v;
#pragma unroll
    for(int o = 1; o < 64; o <<= 1){ int t = __shfl_up(iv, o); if(tid >= o) iv += t; }
    rowoff[tid + 1] = iv;
    cursor[tid]     = iv - v;
    if(tid == 0) rowoff[0] = 0;
  }
  __syncthreads();
#define PUTE(ev) { \
    int rl = (((unsigned)ev.x) >> 16) & 63; \
    int p = atomicAdd(&cursor[rl], 1); \
    unsigned wh = (unsigned)__builtin_bit_cast(unsigned short, \
                    (_Float16)__builtin_bit_cast(float, ev.y)); \
    epk_l[p] = (unsigned)(ev.x & 0xFFFF) | (wh << 16); }
  if(v0) PUTE(e0v);
  if(v1) PUTE(e1v);
  if(v2) PUTE(e2v);
#undef PUTE
  __syncthreads();

  // ---------------- phase 2: aggregation + HypAct (1 row per 8-lane group) ----------------
  const int gi   = tid >> 3;         // 0..63: local row
  const int i    = tid & 7;          // lane within group: dims 16i..16i+15
  const int row  = b * 64 + gi;
  const char* htb = (const char*)ht;
  const int ioff = i << 5;           // 32 B per lane

  half2_t acc2[8];
#pragma unroll
  for(int k = 0; k < 8; k++) acc2[k] = (half2_t){(_Float16)0.f, (_Float16)0.f};

#define EDGE(pk) { \
    int s_ = (int)((pk) & 0xFFFFu); \
    half2_t w2_ = __builtin_bit_cast(half2_t, __builtin_amdgcn_perm(pk, pk, 0x03020302u)); \
    const char* p_ = htb + ((s_ << 8) | ioff); \
    int4 qa = *(const int4*)p_; \
    int4 qb = *(const int4*)(p_ + 16); \
    acc2[0] = __builtin_bit_cast(half2_t, qa.x) * w2_ + acc2[0]; \
    acc2[1] = __builtin_bit_cast(half2_t, qa.y) * w2_ + acc2[1]; \
    acc2[2] = __builtin_bit_cast(half2_t, qa.z) * w2_ + acc2[2]; \
    acc2[3] = __builtin_bit_cast(half2_t, qa.w) * w2_ + acc2[3]; \
    acc2[4] = __builtin_bit_cast(half2_t, qb.x) * w2_ + acc2[4]; \
    acc2[5] = __builtin_bit_cast(half2_t, qb.y) * w2_ + acc2[5]; \
    acc2[6] = __builtin_bit_cast(half2_t, qb.z) * w2_ + acc2[6]; \
    acc2[7] = __builtin_bit_cast(half2_t, qb.w) * w2_ + acc2[7]; \
  }

  if(row < n){
    int beg = rowoff[gi];
    int m   = rowoff[gi + 1] - beg;
    const unsigned* ep = epk_l + beg;
    int t = 0;
    for(; t + 3 < m; t += 4){
      unsigned pk0 = ep[t], pk1 = ep[t+1], pk2 = ep[t+2], pk3 = ep[t+3];
      EDGE(pk0); EDGE(pk1); EDGE(pk2); EDGE(pk3);
    }
    for(; t + 1 < m; t += 2){
      unsigned pk0 = ep[t], pk1 = ep[t+1];
      EDGE(pk0); EDGE(pk1);
    }
    if(t < m){ unsigned pk0 = ep[t]; EDGE(pk0); }
  }
#undef EDGE

  // epilogue: per-group (8-lane) — lane holds 16 contiguous dims
  float acc[16];
#pragma unroll
  for(int k = 0; k < 8; k++){
    acc[2*k]   = (float)acc2[k][0];
    acc[2*k+1] = (float)acc2[k][1];
  }
  float u2p = 0.f;
#pragma unroll
  for(int k = 0; k < 16; k++) u2p = fmaf(acc[k], acc[k], u2p);
  u2p += __shfl_xor(u2p, 1); u2p += __shfl_xor(u2p, 2); u2p += __shfl_xor(u2p, 4);
  float un = fmaxf(sqrtf(u2p), MINN);
  float te = tanhf(un);
  float se = te / un;
  float gn = fmaxf(te, MINN);
  float hn = gn;
  if(gn > MAXN){ se *= MAXN/gn; hn = MAXN; }
  float la = artanh_(hn) / hn * se;
  float l[16];
  float r2p = 0.f;
#pragma unroll
  for(int k = 0; k < 16; k++){ l[k] = fmaxf(la*acc[k], 0.f); r2p = fmaf(l[k], l[k], r2p); }
  r2p += __shfl_xor(r2p, 1); r2p += __shfl_xor(r2p, 2); r2p += __shfl_xor(r2p, 4);
  float rn = fmaxf(sqrtf(r2p), MINN);
  float t2 = tanhf(rn);
  float s2 = t2 / rn;
  float on = fmaxf(t2, MINN);
  if(on > MAXN) s2 *= MAXN/on;

  if(row < n){
    float* orow = out + (size_t)row * 128 + i * 16;
#pragma unroll
    for(int k = 0; k < 4; k++){
      float4 o;
      o.x = s2 * l[4*k];   o.y = s2 * l[4*k+1];
      o.z = s2 * l[4*k+2]; o.w = s2 * l[4*k+3];
      *(float4*)(orow + 4*k) = o;
    }
  }
}

extern "C" void kernel_launch(void* const* d_in, const int* in_sizes, int n_in,
                              void* d_out, int out_size, void* d_ws, size_t ws_size,
                              hipStream_t stream)
{
  const float* x    = (const float*)d_in[0];
  const int*   adj  = (const int*)  d_in[1];
  const float* w    = (const float*)d_in[2];
  const float* W    = (const float*)d_in[3];
  const float* bias = (const float*)d_in[4];
  const int n = in_sizes[0] / 128;   // 50000
  const int E = in_sizes[2];         // 800000

  float* out     = (float*)d_out;
  float* adj_out = out + (size_t)n * 128;

  char* ws = (char*)d_ws;
  _Float16* ht   = (_Float16*)ws;  ws += (size_t)n * 128 * sizeof(_Float16);    // 12.8 MB
  int2*  part    = (int2*)ws;      ws += (size_t)1024 * CAPQ * sizeof(int2);    // 12.6 MB
  int*   bucketSize = (int*)ws;                                                 // 4 KB

  const int nA = (E + 4095) / 4096;   // 196 passA blocks
  const int nS = (n + 63) / 64;       // 782 stageA blocks
  const int nB = (n + 63) / 64;       // 782 aggregation buckets (64 rows each)

  hipMemsetAsync(bucketSize, 0, 1024 * sizeof(int), stream);
  fusedA_kernel<<<nA + nS, 256, 0, stream>>>(x, W, bias, ht, n,
                                             adj, w, adj_out, bucketSize, part, E, nA);
  aggB_kernel<<<nB, 512, 0, stream>>>(bucketSize, part, ht, out, n);
}